// Round 1
// 546.714 us; speedup vs baseline: 1.4226x; 1.4226x over previous
//
#include <hip/hip_runtime.h>
#include <cstddef>

#define T_STEPS 24
#define F_IN 64
#define H_DIM 128
#define ROWS 48
#define TOTAL_ROWS 20800
#define NUM_BLOCKS 434   // ceil(20800 / 48); last block has 16 valid rows

typedef _Float16 f16;
typedef _Float16 half8 __attribute__((ext_vector_type(8)));
typedef float floatx4 __attribute__((ext_vector_type(4)));

#define MFMA16(acc, a, b) (acc) = __builtin_amdgcn_mfma_f32_16x16x32_f16((a), (b), (acc), 0, 0, 0)

// Saturation-safe fast activations: no clamps needed.
// v -> +-inf: exp2 -> inf/0, 1+exp2 -> inf/1, rcp -> 0/1  => correct limits, no NaN.
__device__ __forceinline__ float sigm(float v) {
    return __builtin_amdgcn_rcpf(1.f + __builtin_amdgcn_exp2f(v * -1.44269504f));
}
__device__ __forceinline__ float tanh_(float v) {
    return 1.f - 2.f * __builtin_amdgcn_rcpf(1.f + __builtin_amdgcn_exp2f(v * 2.88539008f));
}

__global__ void cvt_f32_f16(const float* __restrict__ src, f16* __restrict__ dst, int n) {
    int i = blockIdx.x * 256 + threadIdx.x;
    if (i < n) dst[i] = (f16)src[i];
}

// 8 waves/block: wave w owns output columns [16w, 16w+16); 48 rows/block (3 row-tiles
// of 16 per wave). All weight B-fragments stay in registers (168 VGPR/lane), loaded
// once. 3 barriers/step (x staged one step ahead through regs -> no B1). Gate GEMM
// runs entirely in Seg3 so no gate accumulators live across B2.
__global__ __launch_bounds__(512, 2) void gru_fused(
    const float* __restrict__ x,
    const float* __restrict__ b_ih, const float* __restrict__ b_hh,
    const float* __restrict__ gate_b, const float* __restrict__ out_b,
    const f16* __restrict__ wih, const f16* __restrict__ whh,
    const f16* __restrict__ gw, const f16* __restrict__ ow,
    float* __restrict__ out)
{
    __shared__ f16 sX[ROWS][72];       // x_t tile, fp16 (written one step ahead in Seg3)
    __shared__ f16 sH0a[ROWS][136];    // h0 double buffer
    __shared__ f16 sH0b[ROWS][136];
    __shared__ f16 sH1[ROWS][136];     // h1 (single buffer; ordered by B3/B4)
    __shared__ f16 sRH[ROWS][136];     // r * h1

    const int tid  = threadIdx.x;
    const int lane = tid & 63;
    const int wv   = tid >> 6;      // 0..7 -> column tile
    const int p    = lane & 15;     // col-in-tile (B frag) / row-in-tile (A frag)
    const int quad = lane >> 4;     // 0..3
    const int ko   = quad * 8;      // k-offset within a K=32 chunk
    const int c    = wv * 16 + p;   // global output column 0..127
    const int row0 = blockIdx.x * ROWS;
    const bool full = (row0 + ROWS) <= TOTAL_ROWS;

    // x staging role: 384 threads (waves 0..5), 8 floats each -> 48 rows x 64 f
    const int srr = tid >> 3;
    const int sf8 = (tid & 7) * 8;
    const float* xsrc = nullptr;
    floatx4 px0, px1;
    if (tid < 384) {
        int gr = row0 + srr;
        if (gr > TOTAL_ROWS - 1) gr = TOTAL_ROWS - 1;   // clamp for partial last block
        xsrc = x + (size_t)gr * (T_STEPS * F_IN) + sf8;
        px0 = *(const floatx4*)(xsrc);                  // t = 0
        px1 = *(const floatx4*)(xsrc + 4);
    }

    // zero-init h state buffers read at t=0
    for (int i = tid; i < (ROWS * 136) / 2; i += 512) {
        ((unsigned int*)&sH0a[0][0])[i] = 0u;
        ((unsigned int*)&sH1[0][0])[i]  = 0u;
    }

    // per-column biases
    const float bR  = b_ih[c] + b_hh[c];
    const float bZ  = b_ih[128 + c] + b_hh[128 + c];
    const float bIN = b_ih[256 + c];
    const float bHN = b_hh[256 + c];
    const float bGR = gate_b[c];
    const float bGZ = gate_b[128 + c];
    const float bO  = out_b[c];

    // ---- weight-stationary B fragments (n = c, k = kc*32 + quad*8 + j) ----
    half8 Wih[3][2], Whh[3][4], Wgw[2][8], Wow[8];
    #pragma unroll
    for (int g = 0; g < 3; ++g) {
        #pragma unroll
        for (int kc = 0; kc < 2; ++kc)
            Wih[g][kc] = *(const half8*)(wih + (size_t)(g * 128 + c) * 64 + kc * 32 + ko);
        #pragma unroll
        for (int kc = 0; kc < 4; ++kc)
            Whh[g][kc] = *(const half8*)(whh + (size_t)(g * 128 + c) * 128 + kc * 32 + ko);
    }
    #pragma unroll
    for (int g = 0; g < 2; ++g)
        #pragma unroll
        for (int kc = 0; kc < 8; ++kc)
            Wgw[g][kc] = *(const half8*)(gw + (size_t)(g * 128 + c) * 256 + kc * 32 + ko);
    #pragma unroll
    for (int kc = 0; kc < 8; ++kc)
        Wow[kc] = *(const half8*)(ow + (size_t)c * 256 + kc * 32 + ko);

    // recurrent state, fp32, C-layout: element i -> row rt*16 + quad*4 + i, col c
    floatx4 h0p[3], h1p[3], z1[3];
    #pragma unroll
    for (int rt = 0; rt < 3; ++rt) {
        h0p[rt] = (floatx4){0.f, 0.f, 0.f, 0.f};
        h1p[rt] = (floatx4){0.f, 0.f, 0.f, 0.f};
    }

    // write sX(t=0), prefetch x(t=1)
    if (tid < 384) {
        half8 hx;
        #pragma unroll
        for (int j = 0; j < 4; ++j) { hx[j] = (f16)px0[j]; hx[4 + j] = (f16)px1[j]; }
        *(half8*)&sX[srr][sf8] = hx;
        px0 = *(const floatx4*)(xsrc + 64);
        px1 = *(const floatx4*)(xsrc + 68);
    }
    __syncthreads();

    for (int t = 0; t < T_STEPS; ++t) {
        const f16 (*sH0r)[136] = (t & 1) ? sH0b : sH0a;  // old h0
        f16 (*sH0w)[136]       = (t & 1) ? sH0a : sH0b;  // new h0

        // ---- Seg2: layer-0 GRUCell ----
        #pragma unroll
        for (int rt = 0; rt < 3; ++rt) {
            floatx4 aR = (floatx4){0.f, 0.f, 0.f, 0.f};
            floatx4 aZ = aR, aIN = aR, aHN = aR;
            #pragma unroll
            for (int kc = 0; kc < 2; ++kc) {
                const half8 ax = *(const half8*)&sX[rt * 16 + p][kc * 32 + ko];
                MFMA16(aR,  ax, Wih[0][kc]);
                MFMA16(aZ,  ax, Wih[1][kc]);
                MFMA16(aIN, ax, Wih[2][kc]);
            }
            #pragma unroll
            for (int kc = 0; kc < 4; ++kc) {
                const half8 ah = *(const half8*)&sH0r[rt * 16 + p][kc * 32 + ko];
                MFMA16(aR,  ah, Whh[0][kc]);
                MFMA16(aZ,  ah, Whh[1][kc]);
                MFMA16(aHN, ah, Whh[2][kc]);
            }
            #pragma unroll
            for (int i = 0; i < 4; ++i) {
                const float r  = sigm(aR[i] + bR);
                const float z  = sigm(aZ[i] + bZ);
                const float n  = tanh_(aIN[i] + bIN + r * (aHN[i] + bHN));
                const float h0 = n + z * (h0p[rt][i] - n);
                h0p[rt][i] = h0;
                sH0w[rt * 16 + quad * 4 + i][c] = (f16)h0;
            }
        }
        __syncthreads();   // B2: h0new visible

        // ---- Seg3: stage x(t+1) -> sX, issue x(t+2) loads; full gate GEMM ----
        if (t < T_STEPS - 1 && tid < 384) {
            half8 hx;
            #pragma unroll
            for (int j = 0; j < 4; ++j) { hx[j] = (f16)px0[j]; hx[4 + j] = (f16)px1[j]; }
            *(half8*)&sX[srr][sf8] = hx;
            const int tt = (t + 2 < T_STEPS) ? (t + 2) : (T_STEPS - 1);
            px0 = *(const floatx4*)(xsrc + tt * F_IN);
            px1 = *(const floatx4*)(xsrc + tt * F_IN + 4);
        }
        #pragma unroll
        for (int rt = 0; rt < 3; ++rt) {
            floatx4 gR = (floatx4){0.f, 0.f, 0.f, 0.f};
            floatx4 gZ = gR;
            #pragma unroll
            for (int kc = 0; kc < 4; ++kc) {
                const half8 a1 = *(const half8*)&sH1[rt * 16 + p][kc * 32 + ko];
                MFMA16(gR, a1, Wgw[0][4 + kc]);
                MFMA16(gZ, a1, Wgw[1][4 + kc]);
            }
            #pragma unroll
            for (int kc = 0; kc < 4; ++kc) {
                const half8 a0 = *(const half8*)&sH0w[rt * 16 + p][kc * 32 + ko];
                MFMA16(gR, a0, Wgw[0][kc]);
                MFMA16(gZ, a0, Wgw[1][kc]);
            }
            #pragma unroll
            for (int i = 0; i < 4; ++i) {
                const float r1 = sigm(gR[i] + bGR);
                z1[rt][i] = sigm(gZ[i] + bGZ);
                sRH[rt * 16 + quad * 4 + i][c] = (f16)(r1 * h1p[rt][i]);
            }
        }
        __syncthreads();   // B3: sRH (and sX(t+1)) visible

        // ---- Seg4: candidate GEMM + h1 update + output ----
        #pragma unroll
        for (int rt = 0; rt < 3; ++rt) {
            floatx4 aC = (floatx4){0.f, 0.f, 0.f, 0.f};
            #pragma unroll
            for (int kc = 0; kc < 4; ++kc) {
                const half8 a0 = *(const half8*)&sH0w[rt * 16 + p][kc * 32 + ko];
                MFMA16(aC, a0, Wow[kc]);
            }
            #pragma unroll
            for (int kc = 0; kc < 4; ++kc) {
                const half8 ar = *(const half8*)&sRH[rt * 16 + p][kc * 32 + ko];
                MFMA16(aC, ar, Wow[4 + kc]);
            }
            #pragma unroll
            for (int i = 0; i < 4; ++i) {
                const float cd = tanh_(aC[i] + bO);
                const float zz = z1[rt][i];
                const float hv = cd + zz * (h1p[rt][i] - cd);
                h1p[rt][i] = hv;
                sH1[rt * 16 + quad * 4 + i][c] = (f16)hv;
                const int grow = row0 + rt * 16 + quad * 4 + i;
                if (full || grow < TOTAL_ROWS)
                    out[((size_t)grow * T_STEPS + t) * H_DIM + c] = hv;
            }
        }
        __syncthreads();   // B4: h1new visible / sRH-sX consumption ordered
    }
}

extern "C" void kernel_launch(void* const* d_in, const int* in_sizes, int n_in,
                              void* d_out, int out_size, void* d_ws, size_t ws_size,
                              hipStream_t stream) {
    (void)in_sizes; (void)n_in; (void)out_size; (void)ws_size;
    const float* x      = (const float*)d_in[0];
    const float* w_ih   = (const float*)d_in[1];
    const float* w_hh   = (const float*)d_in[2];
    const float* b_ih   = (const float*)d_in[3];
    const float* b_hh   = (const float*)d_in[4];
    const float* gate_w = (const float*)d_in[5];
    const float* gate_b = (const float*)d_in[6];
    const float* out_w  = (const float*)d_in[7];
    const float* out_b  = (const float*)d_in[8];

    f16* wsH = (f16*)d_ws;
    f16* wih = wsH;                 // 384*64   = 24576 halves
    f16* whh = wsH + 24576;         // 384*128  = 49152
    f16* gw  = wsH + 73728;         // 256*256  = 65536
    f16* ow  = wsH + 139264;        // 128*256  = 32768

    cvt_f32_f16<<<(24576 + 255) / 256, 256, 0, stream>>>(w_ih, wih, 24576);
    cvt_f32_f16<<<(49152 + 255) / 256, 256, 0, stream>>>(w_hh, whh, 49152);
    cvt_f32_f16<<<(65536 + 255) / 256, 256, 0, stream>>>(gate_w, gw, 65536);
    cvt_f32_f16<<<(32768 + 255) / 256, 256, 0, stream>>>(out_w, ow, 32768);

    gru_fused<<<NUM_BLOCKS, 512, 0, stream>>>(x, b_ih, b_hh, gate_b, out_b,
                                              wih, whh, gw, ow, (float*)d_out);
}